// Round 1
// baseline (879.756 us; speedup 1.0000x reference)
//
#include <hip/hip_runtime.h>

#define SDIM 196
#define BDIM 64
#define NDIM 512
#define DDIM 1024
#define HDIM 8

typedef __attribute__((ext_vector_type(8))) short short8;
typedef __attribute__((ext_vector_type(8))) unsigned short ushort8;
typedef __attribute__((ext_vector_type(4))) float f32x4;

__device__ __forceinline__ unsigned short f2bf(float f) {
    unsigned int x = __float_as_uint(f);
    x += 0x7fffu + ((x >> 16) & 1u);   // round-to-nearest-even
    return (unsigned short)(x >> 16);
}

__device__ __forceinline__ float wred_sum(float v) {
#pragma unroll
    for (int off = 32; off > 0; off >>= 1) v += __shfl_down(v, off);
    return v;
}

// ---------------- g = mean_s(input); also writes common[:,0,:] ----------------
__global__ __launch_bounds__(256) void k_mean_g(const float* __restrict__ in,
                                                float* __restrict__ g,
                                                float* __restrict__ common) {
    int idx = (blockIdx.x * 256 + threadIdx.x) * 4;   // over B*D = 65536
    float4 acc = make_float4(0.f, 0.f, 0.f, 0.f);
    for (int s = 0; s < SDIM; s++) {
        float4 v = *(const float4*)(in + (size_t)s * (BDIM * DDIM) + idx);
        acc.x += v.x; acc.y += v.y; acc.z += v.z; acc.w += v.w;
    }
    const float r = 1.f / (float)SDIM;
    acc.x *= r; acc.y *= r; acc.z *= r; acc.w *= r;
    *(float4*)(g + idx) = acc;
    int b = idx >> 10, d = idx & 1023;
    *(float4*)(common + ((size_t)b * 9) * DDIM + d) = acc;
}

// ---------------- W1 (upd_W rows 0..1023) -> W1t[e][d] bf16 ----------------
__global__ __launch_bounds__(256) void k_w1t(const float* __restrict__ W,
                                             unsigned short* __restrict__ Wt) {
    __shared__ float tile[64][65];
    int d0 = blockIdx.y * 64, e0 = blockIdx.x * 64;
    int t = threadIdx.x;
    for (int rep = 0; rep < 16; rep++) {
        int idx = rep * 256 + t;
        int dl = idx >> 6, el = idx & 63;
        tile[dl][el] = W[(size_t)(d0 + dl) * DDIM + e0 + el];
    }
    __syncthreads();
    for (int rep = 0; rep < 16; rep++) {
        int idx = rep * 256 + t;
        int el = idx >> 6, dl = idx & 63;
        Wt[(size_t)(e0 + el) * DDIM + d0 + dl] = f2bf(tile[dl][el]);
    }
}

// ---------------- generic tiled SGEMM, C = A@B (+bias), 64x64 tile ----------------
// grid (N/64, M/64, batch); K mult of 32, M,N mult of 64.
__global__ __launch_bounds__(256) void k_sgemm_nn(const float* __restrict__ A,
                                                  const float* __restrict__ B,
                                                  const float* __restrict__ bias,
                                                  float* __restrict__ C,
                                                  int K, int lda, int ldb, int ldc,
                                                  long sA, long sB, long sBias, long sC) {
    int z = blockIdx.z;
    A += (size_t)z * sA; B += (size_t)z * sB; C += (size_t)z * sC;
    if (bias) bias += (size_t)z * sBias;
    __shared__ float As[64][36];
    __shared__ float Bs[32][68];
    int t = threadIdx.x;
    int tx = t & 15, ty = t >> 4;
    int n0 = blockIdx.x * 64, m0 = blockIdx.y * 64;
    float acc[4][4] = {};
    int ra = t >> 2, ca = (t & 3) * 8;
    int rb = t >> 3, cb = (t & 7) * 8;
    for (int k0 = 0; k0 < K; k0 += 32) {
        float4 a0 = *(const float4*)(A + (size_t)(m0 + ra) * lda + k0 + ca);
        float4 a1 = *(const float4*)(A + (size_t)(m0 + ra) * lda + k0 + ca + 4);
        *(float4*)&As[ra][ca] = a0;
        *(float4*)&As[ra][ca + 4] = a1;
        float4 b0 = *(const float4*)(B + (size_t)(k0 + rb) * ldb + n0 + cb);
        float4 b1 = *(const float4*)(B + (size_t)(k0 + rb) * ldb + n0 + cb + 4);
        *(float4*)&Bs[rb][cb] = b0;
        *(float4*)&Bs[rb][cb + 4] = b1;
        __syncthreads();
#pragma unroll 8
        for (int kk = 0; kk < 32; kk++) {
            float av[4];
#pragma unroll
            for (int i = 0; i < 4; i++) av[i] = As[ty * 4 + i][kk];
            float4 bv = *(const float4*)&Bs[kk][tx * 4];
            float bw[4] = {bv.x, bv.y, bv.z, bv.w};
#pragma unroll
            for (int i = 0; i < 4; i++)
#pragma unroll
                for (int j = 0; j < 4; j++) acc[i][j] += av[i] * bw[j];
        }
        __syncthreads();
    }
    int n = n0 + tx * 4;
    float4 bv = bias ? *(const float4*)(bias + n) : make_float4(0.f, 0.f, 0.f, 0.f);
#pragma unroll
    for (int i = 0; i < 4; i++) {
        int m = m0 + ty * 4 + i;
        float4 o;
        o.x = acc[i][0] + bv.x; o.y = acc[i][1] + bv.y;
        o.z = acc[i][2] + bv.z; o.w = acc[i][3] + bv.w;
        *(float4*)(C + (size_t)m * ldc + n) = o;
    }
}

// C[m,n] = sum_k A[m,k]*B[n,k] (+bias[n]) — both operands k-contiguous
__global__ __launch_bounds__(256) void k_sgemm_nt(const float* __restrict__ A,
                                                  const float* __restrict__ B,
                                                  const float* __restrict__ bias,
                                                  float* __restrict__ C,
                                                  int K, int lda, int ldb, int ldc,
                                                  long sA, long sB, long sBias, long sC) {
    int z = blockIdx.z;
    A += (size_t)z * sA; B += (size_t)z * sB; C += (size_t)z * sC;
    if (bias) bias += (size_t)z * sBias;
    __shared__ float As[64][33];
    __shared__ float Bs[64][33];
    int t = threadIdx.x;
    int tx = t & 15, ty = t >> 4;
    int n0 = blockIdx.x * 64, m0 = blockIdx.y * 64;
    float acc[4][4] = {};
    int ra = t >> 2, ca = (t & 3) * 8;
    for (int k0 = 0; k0 < K; k0 += 32) {
        float4 a0 = *(const float4*)(A + (size_t)(m0 + ra) * lda + k0 + ca);
        float4 a1 = *(const float4*)(A + (size_t)(m0 + ra) * lda + k0 + ca + 4);
        As[ra][ca + 0] = a0.x; As[ra][ca + 1] = a0.y; As[ra][ca + 2] = a0.z; As[ra][ca + 3] = a0.w;
        As[ra][ca + 4] = a1.x; As[ra][ca + 5] = a1.y; As[ra][ca + 6] = a1.z; As[ra][ca + 7] = a1.w;
        float4 b0 = *(const float4*)(B + (size_t)(n0 + ra) * ldb + k0 + ca);
        float4 b1 = *(const float4*)(B + (size_t)(n0 + ra) * ldb + k0 + ca + 4);
        Bs[ra][ca + 0] = b0.x; Bs[ra][ca + 1] = b0.y; Bs[ra][ca + 2] = b0.z; Bs[ra][ca + 3] = b0.w;
        Bs[ra][ca + 4] = b1.x; Bs[ra][ca + 5] = b1.y; Bs[ra][ca + 6] = b1.z; Bs[ra][ca + 7] = b1.w;
        __syncthreads();
#pragma unroll 8
        for (int kk = 0; kk < 32; kk++) {
            float av[4], bw[4];
#pragma unroll
            for (int i = 0; i < 4; i++) av[i] = As[ty * 4 + i][kk];
#pragma unroll
            for (int j = 0; j < 4; j++) bw[j] = Bs[tx * 4 + j][kk];
#pragma unroll
            for (int i = 0; i < 4; i++)
#pragma unroll
                for (int j = 0; j < 4; j++) acc[i][j] += av[i] * bw[j];
        }
        __syncthreads();
    }
    int n = n0 + tx * 4;
    float4 bv = bias ? *(const float4*)(bias + n) : make_float4(0.f, 0.f, 0.f, 0.f);
#pragma unroll
    for (int i = 0; i < 4; i++) {
        int m = m0 + ty * 4 + i;
        float4 o;
        o.x = acc[i][0] + bv.x; o.y = acc[i][1] + bv.y;
        o.z = acc[i][2] + bv.z; o.w = acc[i][3] + bv.w;
        *(float4*)(C + (size_t)m * ldc + n) = o;
    }
}

// ---------------- qkb[b,h] = sum_e Q[b,h,e]*bk[h,e] ----------------
__global__ __launch_bounds__(256) void k_qkb(const float* __restrict__ Q,
                                             const float* __restrict__ bk,
                                             float* __restrict__ qkb) {
    int b = blockIdx.x, t = threadIdx.x;
    int wave = t >> 6, lane = t & 63;
    for (int h = wave; h < HDIM; h += 4) {
        const float* q = Q + (size_t)b * (HDIM * DDIM) + h * DDIM;
        const float* bkh = bk + h * DDIM;
        float a = 0.f;
        for (int e = lane; e < DDIM; e += 64) a += q[e] * bkh[e];
        a = wred_sum(a);
        if (lane == 0) qkb[b * HDIM + h] = a;
    }
}

// ---------------- M[b,h,n] = (gn[b,n,:]·Qt[b,h,:] + qkb)/32 ----------------
__global__ __launch_bounds__(256) void k_scores(const float* __restrict__ gn,
                                                const float* __restrict__ Qt,
                                                const float* __restrict__ qkb,
                                                float* __restrict__ M) {
    int b = blockIdx.y;
    int wave = threadIdx.x >> 6, lane = threadIdx.x & 63;
    int n = blockIdx.x * 4 + wave;
    const float* gr = gn + ((size_t)b * NDIM + n) * DDIM;
    const float* qtb = Qt + (size_t)b * (HDIM * DDIM);
    float acc[HDIM];
#pragma unroll
    for (int h = 0; h < HDIM; h++) acc[h] = 0.f;
    for (int d = lane; d < DDIM; d += 64) {
        float v = gr[d];
#pragma unroll
        for (int h = 0; h < HDIM; h++) acc[h] += v * qtb[h * DDIM + d];
    }
#pragma unroll
    for (int h = 0; h < HDIM; h++) acc[h] = wred_sum(acc[h]);
    if (lane == 0) {
#pragma unroll
        for (int h = 0; h < HDIM; h++)
            M[((size_t)b * HDIM + h) * NDIM + n] = (acc[h] + qkb[b * HDIM + h]) * 0.03125f;
    }
}

// ---------------- softmax over n (512), in place ----------------
__global__ __launch_bounds__(256) void k_softmax_n(float* __restrict__ M) {
    int h = blockIdx.x, b = blockIdx.y, t = threadIdx.x;
    float* p = M + ((size_t)b * HDIM + h) * NDIM;
    float v0 = p[t], v1 = p[t + 256];
    float m = fmaxf(v0, v1);
#pragma unroll
    for (int off = 32; off > 0; off >>= 1) m = fmaxf(m, __shfl_down(m, off));
    __shared__ float r1[4], r2[4];
    int wave = t >> 6, lane = t & 63;
    if (lane == 0) r1[wave] = m;
    __syncthreads();
    m = fmaxf(fmaxf(r1[0], r1[1]), fmaxf(r1[2], r1[3]));
    float e0 = __expf(v0 - m), e1 = __expf(v1 - m);
    float s = e0 + e1;
    s = wred_sum(s);
    if (lane == 0) r2[wave] = s;
    __syncthreads();
    s = r2[0] + r2[1] + r2[2] + r2[3];
    float inv = 1.f / s;
    p[t] = e0 * inv;
    p[t + 256] = e1 * inv;
}

// ---------------- closest[b,h,:] = attn[b,h,:]@gn[b] -> common rows 1..8 ----------------
__global__ __launch_bounds__(256) void k_closest(const float* __restrict__ gn,
                                                 const float* __restrict__ attn,
                                                 float* __restrict__ common) {
    int b = blockIdx.y;
    int d = blockIdx.x * 256 + threadIdx.x;
    const float* gb = gn + (size_t)b * NDIM * DDIM + d;
    const float* ab = attn + (size_t)b * HDIM * NDIM;
    float acc[HDIM];
#pragma unroll
    for (int h = 0; h < HDIM; h++) acc[h] = 0.f;
    for (int n = 0; n < NDIM; n++) {
        float v = gb[(size_t)n * DDIM];
#pragma unroll
        for (int h = 0; h < HDIM; h++) acc[h] += ab[h * NDIM + n] * v;
    }
#pragma unroll
    for (int h = 0; h < HDIM; h++)
        common[((size_t)b * 9 + 1 + h) * DDIM + d] = acc[h];
}

// ---------------- diff attention (9x9) + diff = g - common_info ----------------
__global__ __launch_bounds__(256) void k_diff(const float* __restrict__ Qd,
                                              const float* __restrict__ Kd,
                                              const float* __restrict__ common,
                                              const float* __restrict__ g,
                                              float* __restrict__ diffb) {
    int b = blockIdx.x, t = threadIdx.x;
    int wave = t >> 6, lane = t & 63;
    __shared__ float smd[81];
    __shared__ float sw[9];
    for (int p = wave; p < 81; p += 4) {
        int i = p / 9, j = p % 9;
        const float* qi = Qd + ((size_t)b * 9 + i) * DDIM;
        const float* kj = Kd + ((size_t)b * 9 + j) * DDIM;
        float a = 0.f;
        for (int d = lane; d < DDIM; d += 64) a += qi[d] * kj[d];
        a = wred_sum(a);
        if (lane == 0) smd[p] = a * 0.03125f;
    }
    __syncthreads();
    if (t < 9) {
        float mx = -1e30f;
        for (int j = 0; j < 9; j++) mx = fmaxf(mx, smd[t * 9 + j]);
        float e[9], s = 0.f;
        for (int j = 0; j < 9; j++) { e[j] = __expf(smd[t * 9 + j] - mx); s += e[j]; }
        float inv = 1.f / s;
        for (int j = 0; j < 9; j++) smd[t * 9 + j] = e[j] * inv;
    }
    __syncthreads();
    if (t < 9) {
        float a = 0.f;
        for (int i = 0; i < 9; i++) a += smd[i * 9 + t];
        sw[t] = a * (1.f / 9.f);
    }
    __syncthreads();
    for (int d = t; d < DDIM; d += 256) {
        float ci = 0.f;
#pragma unroll
        for (int j = 0; j < 9; j++) ci += sw[j] * common[((size_t)b * 9 + j) * DDIM + d];
        diffb[(size_t)b * DDIM + d] = g[(size_t)b * DDIM + d] - ci;
    }
}

// ---------------- main GEMM: h = relu(input@W1 + dt2[b]) -> d_out (bf16 MFMA) ----------------
// grid (1024/64=16, 12544/64=196), 256 thr (4 waves, 2x2 over 64x64 tile)
__global__ __launch_bounds__(256) void k_gemm_main(const float* __restrict__ A,
                                                   const unsigned short* __restrict__ Wt,
                                                   const float* __restrict__ dt2,
                                                   float* __restrict__ out) {
    __shared__ unsigned short As[64][40];   // [m][k] bf16, pad 40 to break 8-way banks
    __shared__ unsigned short Bs[64][40];   // [e][k] bf16
    int t = threadIdx.x;
    int lane = t & 63, wave = t >> 6;
    int quad = lane >> 4, l16 = lane & 15;
    int wr = wave >> 1, wc = wave & 1;
    int m0 = blockIdx.y * 64, n0 = blockIdx.x * 64;
    f32x4 acc[2][2];
#pragma unroll
    for (int i = 0; i < 2; i++)
#pragma unroll
        for (int j = 0; j < 2; j++)
#pragma unroll
            for (int rr = 0; rr < 4; rr++) acc[i][j][rr] = 0.f;
    int r = t >> 2, c = (t & 3) * 8;
    for (int k0 = 0; k0 < DDIM; k0 += 32) {
        float4 v0 = *(const float4*)(A + (size_t)(m0 + r) * DDIM + k0 + c);
        float4 v1 = *(const float4*)(A + (size_t)(m0 + r) * DDIM + k0 + c + 4);
        ushort8 u;
        u[0] = f2bf(v0.x); u[1] = f2bf(v0.y); u[2] = f2bf(v0.z); u[3] = f2bf(v0.w);
        u[4] = f2bf(v1.x); u[5] = f2bf(v1.y); u[6] = f2bf(v1.z); u[7] = f2bf(v1.w);
        *(ushort8*)&As[r][c] = u;
        *(ushort8*)&Bs[r][c] = *(const ushort8*)(Wt + (size_t)(n0 + r) * DDIM + k0 + c);
        __syncthreads();
        short8 a0 = *(const short8*)&As[wr * 32 + l16][quad * 8];
        short8 a1 = *(const short8*)&As[wr * 32 + 16 + l16][quad * 8];
        short8 b0 = *(const short8*)&Bs[wc * 32 + l16][quad * 8];
        short8 b1 = *(const short8*)&Bs[wc * 32 + 16 + l16][quad * 8];
        acc[0][0] = __builtin_amdgcn_mfma_f32_16x16x32_bf16(a0, b0, acc[0][0], 0, 0, 0);
        acc[0][1] = __builtin_amdgcn_mfma_f32_16x16x32_bf16(a0, b1, acc[0][1], 0, 0, 0);
        acc[1][0] = __builtin_amdgcn_mfma_f32_16x16x32_bf16(a1, b0, acc[1][0], 0, 0, 0);
        acc[1][1] = __builtin_amdgcn_mfma_f32_16x16x32_bf16(a1, b1, acc[1][1], 0, 0, 0);
        __syncthreads();
    }
    // C/D layout: col = lane&15, row = quad*4 + reg. b-index = local row (tile M == B == 64).
#pragma unroll
    for (int tm = 0; tm < 2; tm++)
#pragma unroll
        for (int tn = 0; tn < 2; tn++) {
            int col = n0 + wc * 32 + tn * 16 + l16;
#pragma unroll
            for (int rr = 0; rr < 4; rr++) {
                int ml = wr * 32 + tm * 16 + quad * 4 + rr;
                float v = acc[tm][tn][rr] + dt2[ml * DDIM + col];
                out[(size_t)(m0 + ml) * DDIM + col] = fmaxf(v, 0.f);
            }
        }
}

// ---------------- in-place LayerNorm over D ----------------
__global__ __launch_bounds__(256) void k_ln(float* __restrict__ io,
                                            const float* __restrict__ gamma,
                                            const float* __restrict__ beta) {
    size_t row = blockIdx.x;
    float* p = io + row * DDIM;
    int t = threadIdx.x;
    float4 v = *(const float4*)(p + t * 4);
    float s = v.x + v.y + v.z + v.w;
    float s2 = v.x * v.x + v.y * v.y + v.z * v.z + v.w * v.w;
    s = wred_sum(s);
    s2 = wred_sum(s2);
    __shared__ float r1[4], r2[4], mv[2];
    int wave = t >> 6, lane = t & 63;
    if (lane == 0) { r1[wave] = s; r2[wave] = s2; }
    __syncthreads();
    if (t == 0) {
        float S = r1[0] + r1[1] + r1[2] + r1[3];
        float S2 = r2[0] + r2[1] + r2[2] + r2[3];
        float mean = S * (1.f / DDIM);
        float var = S2 * (1.f / DDIM) - mean * mean;
        mv[0] = mean;
        mv[1] = rsqrtf(var + 1e-5f);
    }
    __syncthreads();
    float mean = mv[0], rstd = mv[1];
    float4 gg = *(const float4*)(gamma + t * 4);
    float4 bb = *(const float4*)(beta + t * 4);
    float4 o;
    o.x = (v.x - mean) * rstd * gg.x + bb.x;
    o.y = (v.y - mean) * rstd * gg.y + bb.y;
    o.z = (v.z - mean) * rstd * gg.z + bb.z;
    o.w = (v.w - mean) * rstd * gg.w + bb.w;
    *(float4*)(p + t * 4) = o;
}

extern "C" void kernel_launch(void* const* d_in, const int* in_sizes, int n_in,
                              void* d_out, int out_size, void* d_ws, size_t ws_size,
                              hipStream_t stream) {
    (void)in_sizes; (void)n_in; (void)out_size; (void)ws_size;
    const float* input = (const float*)d_in[0];
    const float* gn    = (const float*)d_in[1];
    const float* aWq   = (const float*)d_in[2];
    const float* abq   = (const float*)d_in[3];
    const float* aWk   = (const float*)d_in[4];
    const float* abk   = (const float*)d_in[5];
    const float* dWq   = (const float*)d_in[6];
    const float* dbq   = (const float*)d_in[7];
    const float* dWk   = (const float*)d_in[8];
    const float* dbk   = (const float*)d_in[9];
    const float* uW    = (const float*)d_in[10];
    const float* ub    = (const float*)d_in[11];
    const float* lng   = (const float*)d_in[12];
    const float* lnb   = (const float*)d_in[13];
    float* out = (float*)d_out;

    float* ws = (float*)d_ws;
    float* g      = ws;                    // 65536
    float* Q      = g + 65536;             // 524288  [B][H][D]
    float* Qt     = Q + 524288;            // 524288  [B][H][D]
    float* qkb    = Qt + 524288;           // 1024 (padded)
    float* Mbuf   = qkb + 1024;            // 262144  [B][H][N]
    float* common = Mbuf + 262144;         // 589824  [B][9][D]
    float* Qd     = common + 589824;       // 589824
    float* Kd     = Qd + 589824;           // 589824
    float* diffb  = Kd + 589824;           // 65536
    float* dt2    = diffb + 65536;         // 65536
    unsigned short* W1t = (unsigned short*)(dt2 + 65536);  // 1M bf16

    k_w1t<<<dim3(16, 16), 256, 0, stream>>>(uW, W1t);
    k_mean_g<<<64, 256, 0, stream>>>(input, g, common);
    // Q[b,h,:] = g[b]@aWq[h] + abq[h]
    k_sgemm_nn<<<dim3(16, 1, 8), 256, 0, stream>>>(g, aWq, abq, Q,
        DDIM, DDIM, DDIM, HDIM * DDIM, 0L, (long)DDIM * DDIM, (long)DDIM, (long)DDIM);
    // Qt[b,h,:] = Q[b,h,:] @ aWk[h]^T   (nt: B rows are d, k = e)
    k_sgemm_nt<<<dim3(16, 1, 8), 256, 0, stream>>>(Q, aWk, nullptr, Qt,
        DDIM, HDIM * DDIM, DDIM, HDIM * DDIM, (long)DDIM, (long)DDIM * DDIM, 0L, (long)DDIM);
    k_qkb<<<64, 256, 0, stream>>>(Q, abk, qkb);
    k_scores<<<dim3(NDIM / 4, BDIM), 256, 0, stream>>>(gn, Qt, qkb, Mbuf);
    k_softmax_n<<<dim3(HDIM, BDIM), 256, 0, stream>>>(Mbuf);
    k_closest<<<dim3(DDIM / 256, BDIM), 256, 0, stream>>>(gn, Mbuf, common);
    // Qd/Kd = common @ dW{q,k} + db{q,k}   (M = 576)
    k_sgemm_nn<<<dim3(16, 9, 1), 256, 0, stream>>>(common, dWq, dbq, Qd,
        DDIM, DDIM, DDIM, DDIM, 0L, 0L, 0L, 0L);
    k_sgemm_nn<<<dim3(16, 9, 1), 256, 0, stream>>>(common, dWk, dbk, Kd,
        DDIM, DDIM, DDIM, DDIM, 0L, 0L, 0L, 0L);
    k_diff<<<64, 256, 0, stream>>>(Qd, Kd, common, g, diffb);
    // dt2[b,:] = diff[b]@W2 + upd_b
    k_sgemm_nn<<<dim3(16, 1, 1), 256, 0, stream>>>(diffb, uW + (size_t)DDIM * DDIM, ub, dt2,
        DDIM, DDIM, DDIM, DDIM, 0L, 0L, 0L, 0L);
    k_gemm_main<<<dim3(DDIM / 64, (SDIM * BDIM) / 64), 256, 0, stream>>>(input, W1t, dt2, out);
    k_ln<<<SDIM * BDIM, 256, 0, stream>>>(out, lng, lnb);
}

// Round 2
// 701.437 us; speedup vs baseline: 1.2542x; 1.2542x over previous
//
#include <hip/hip_runtime.h>

#define SDIM 196
#define BDIM 64
#define NDIM 512
#define DDIM 1024
#define HDIM 8

typedef __attribute__((ext_vector_type(8))) short short8;
typedef __attribute__((ext_vector_type(8))) unsigned short ushort8;
typedef __attribute__((ext_vector_type(4))) unsigned short ushort4v;
typedef __attribute__((ext_vector_type(4))) float f32x4;

typedef const __attribute__((address_space(1))) unsigned int* gq_ptr;
typedef __attribute__((address_space(3))) unsigned int* lds_ptr;

__device__ __forceinline__ unsigned short f2bf(float f) {
    unsigned int x = __float_as_uint(f);
    x += 0x7fffu + ((x >> 16) & 1u);   // RNE
    return (unsigned short)(x >> 16);
}

__device__ __forceinline__ float wred_sum(float v) {
#pragma unroll
    for (int off = 32; off > 0; off >>= 1) v += __shfl_down(v, off);
    return v;
}
__device__ __forceinline__ float bfly_max(float v) {
#pragma unroll
    for (int off = 1; off < 64; off <<= 1) v = fmaxf(v, __shfl_xor(v, off));
    return v;
}
__device__ __forceinline__ float bfly_sum(float v) {
#pragma unroll
    for (int off = 1; off < 64; off <<= 1) v += __shfl_xor(v, off);
    return v;
}

// ---------------- input -> bf16 copy + partial sums over s (7 chunks of 28) ----------------
__global__ __launch_bounds__(256) void k_mean_cast(const float* __restrict__ in,
                                                   unsigned short* __restrict__ Abf,
                                                   float* __restrict__ gpart) {
    int idx4 = blockIdx.x * 256 + threadIdx.x;   // 0..16383 over B*D/4
    int z = blockIdx.y;                           // 0..6
    size_t base = (size_t)idx4 * 4;
    float4 acc = make_float4(0.f, 0.f, 0.f, 0.f);
    int s0 = z * 28;
    for (int s = s0; s < s0 + 28; s++) {
        float4 v = *(const float4*)(in + (size_t)s * 65536 + base);
        acc.x += v.x; acc.y += v.y; acc.z += v.z; acc.w += v.w;
        ushort4v u;
        u[0] = f2bf(v.x); u[1] = f2bf(v.y); u[2] = f2bf(v.z); u[3] = f2bf(v.w);
        *(ushort4v*)(Abf + (size_t)s * 65536 + base) = u;
    }
    *(float4*)(gpart + (size_t)z * 65536 + base) = acc;
}

// ---------------- finalize g (fp32 + bf16), write common row 0 ----------------
__global__ __launch_bounds__(256) void k_gfinal(const float* __restrict__ gpart,
                                                float* __restrict__ g,
                                                unsigned short* __restrict__ g_bf,
                                                float* __restrict__ common,
                                                unsigned short* __restrict__ common_bf) {
    int idx4 = blockIdx.x * 256 + threadIdx.x;
    size_t base = (size_t)idx4 * 4;
    float4 s = make_float4(0.f, 0.f, 0.f, 0.f);
#pragma unroll
    for (int z = 0; z < 7; z++) {
        float4 v = *(const float4*)(gpart + (size_t)z * 65536 + base);
        s.x += v.x; s.y += v.y; s.z += v.z; s.w += v.w;
    }
    const float r = 1.f / (float)SDIM;
    s.x *= r; s.y *= r; s.z *= r; s.w *= r;
    *(float4*)(g + base) = s;
    ushort4v u;
    u[0] = f2bf(s.x); u[1] = f2bf(s.y); u[2] = f2bf(s.z); u[3] = f2bf(s.w);
    *(ushort4v*)(g_bf + base) = u;
    int b = (int)(base >> 10), d = (int)(base & 1023);
    size_t o = ((size_t)b * 9) * DDIM + d;
    *(float4*)(common + o) = s;
    *(ushort4v*)(common_bf + o) = u;
}

// ---------------- all weight casts / transposes in one launch ----------------
// z<8: aWq[h] [d][e] -> aWqT[h] [e][d] bf16 ; z=8: dWq T ; z=9: dWk T ; z=10: uW rows0..1023 T
// z in 11..18: aWk[h] copy-cast (already k-major for Qt)
__global__ __launch_bounds__(256) void k_prep_w(const float* __restrict__ aWq,
                                                const float* __restrict__ dWq,
                                                const float* __restrict__ dWk,
                                                const float* __restrict__ uW,
                                                const float* __restrict__ aWk,
                                                unsigned short* __restrict__ aWqT,
                                                unsigned short* __restrict__ dWqT,
                                                unsigned short* __restrict__ dWkT,
                                                unsigned short* __restrict__ W1t,
                                                unsigned short* __restrict__ aWkb) {
    __shared__ float tile[64][65];
    int z = blockIdx.z;
    const float* src; unsigned short* dst; bool tr = true;
    if (z < 8)       { src = aWq + (size_t)z * 1048576; dst = aWqT + (size_t)z * 1048576; }
    else if (z == 8) { src = dWq; dst = dWqT; }
    else if (z == 9) { src = dWk; dst = dWkT; }
    else if (z == 10){ src = uW;  dst = W1t; }
    else             { src = aWk + (size_t)(z - 11) * 1048576; dst = aWkb + (size_t)(z - 11) * 1048576; tr = false; }
    int d0 = blockIdx.y * 64, e0 = blockIdx.x * 64, t = threadIdx.x;
    if (tr) {
        for (int rep = 0; rep < 16; rep++) {
            int idx = rep * 256 + t;
            int dl = idx >> 6, el = idx & 63;
            tile[dl][el] = src[(size_t)(d0 + dl) * DDIM + e0 + el];
        }
        __syncthreads();
        for (int rep = 0; rep < 16; rep++) {
            int idx = rep * 256 + t;
            int el = idx >> 6, dl = idx & 63;
            dst[(size_t)(e0 + el) * DDIM + d0 + dl] = f2bf(tile[dl][el]);
        }
    } else {
        for (int rep = 0; rep < 16; rep++) {
            int idx = rep * 256 + t;
            int dl = idx >> 6, el = idx & 63;
            size_t o = (size_t)(d0 + dl) * DDIM + e0 + el;
            dst[o] = f2bf(src[o]);
        }
    }
}

// ---------------- generic bf16 MFMA GEMM, 64x64 tile, K=1024, lda=ldb=ldc=1024 ----------------
// z-batched with two parameter sets: z<zsplit -> set0 (zz=z), else set1 (zz=z-zsplit)
__global__ __launch_bounds__(256) void k_mfma64(const unsigned short* __restrict__ A,
                                                const unsigned short* __restrict__ B0,
                                                const unsigned short* __restrict__ B1,
                                                const float* __restrict__ bias0,
                                                const float* __restrict__ bias1,
                                                float* __restrict__ C0,
                                                float* __restrict__ C1,
                                                unsigned short* __restrict__ Cbf,
                                                long sA, long sB, long sBias, long sC,
                                                int zsplit) {
    __shared__ unsigned short As[64][40];
    __shared__ unsigned short Bs[64][40];
    int z = blockIdx.z;
    const unsigned short* Bp; const float* bp; float* Cp; int zz;
    if (z < zsplit) { Bp = B0; bp = bias0; Cp = C0; zz = z; }
    else            { Bp = B1; bp = bias1; Cp = C1; zz = z - zsplit; }
    A  += (size_t)zz * sA;
    Bp += (size_t)zz * sB;
    if (bp) bp += (size_t)zz * sBias;
    Cp += (size_t)zz * sC;
    unsigned short* Cb = Cbf ? Cbf + (size_t)zz * sC : nullptr;

    int t = threadIdx.x;
    int lane = t & 63, wave = t >> 6;
    int quad = lane >> 4, l16 = lane & 15;
    int wr = wave >> 1, wc = wave & 1;
    int m0 = blockIdx.y * 64, n0 = blockIdx.x * 64;
    f32x4 acc[2][2];
#pragma unroll
    for (int i = 0; i < 2; i++)
#pragma unroll
        for (int j = 0; j < 2; j++)
#pragma unroll
            for (int rr = 0; rr < 4; rr++) acc[i][j][rr] = 0.f;
    int r = t >> 2, c = (t & 3) * 8;
    for (int k0 = 0; k0 < DDIM; k0 += 32) {
        *(ushort8*)&As[r][c] = *(const ushort8*)(A  + (size_t)(m0 + r) * DDIM + k0 + c);
        *(ushort8*)&Bs[r][c] = *(const ushort8*)(Bp + (size_t)(n0 + r) * DDIM + k0 + c);
        __syncthreads();
        short8 a0 = *(const short8*)&As[wr * 32 + l16][quad * 8];
        short8 a1 = *(const short8*)&As[wr * 32 + 16 + l16][quad * 8];
        short8 b0 = *(const short8*)&Bs[wc * 32 + l16][quad * 8];
        short8 b1 = *(const short8*)&Bs[wc * 32 + 16 + l16][quad * 8];
        acc[0][0] = __builtin_amdgcn_mfma_f32_16x16x32_bf16(a0, b0, acc[0][0], 0, 0, 0);
        acc[0][1] = __builtin_amdgcn_mfma_f32_16x16x32_bf16(a0, b1, acc[0][1], 0, 0, 0);
        acc[1][0] = __builtin_amdgcn_mfma_f32_16x16x32_bf16(a1, b0, acc[1][0], 0, 0, 0);
        acc[1][1] = __builtin_amdgcn_mfma_f32_16x16x32_bf16(a1, b1, acc[1][1], 0, 0, 0);
        __syncthreads();
    }
#pragma unroll
    for (int tm = 0; tm < 2; tm++)
#pragma unroll
        for (int tn = 0; tn < 2; tn++) {
            int col = n0 + wc * 32 + tn * 16 + l16;
            float bb = bp ? bp[col] : 0.f;
#pragma unroll
            for (int rr = 0; rr < 4; rr++) {
                int m = m0 + wr * 32 + tm * 16 + quad * 4 + rr;
                float v = acc[tm][tn][rr] + bb;
                Cp[(size_t)m * DDIM + col] = v;
                if (Cb) Cb[(size_t)m * DDIM + col] = f2bf(v);
            }
        }
}

// ---------------- M[b,h,n] = gn[b,n,:]·Qt[h,b,:] / 32 (qkb added later) ----------------
__global__ __launch_bounds__(256) void k_scores(const float* __restrict__ gn,
                                                const float* __restrict__ Qt,
                                                float* __restrict__ M) {
    int b = blockIdx.y;
    int wave = threadIdx.x >> 6, lane = threadIdx.x & 63;
    int n = blockIdx.x * 4 + wave;
    const float* gr = gn + ((size_t)b * NDIM + n) * DDIM;
    const float* qtb = Qt + (size_t)b * DDIM;   // + h*65536
    float acc[HDIM];
#pragma unroll
    for (int h = 0; h < HDIM; h++) acc[h] = 0.f;
    for (int d = lane; d < DDIM; d += 64) {
        float v = gr[d];
#pragma unroll
        for (int h = 0; h < HDIM; h++) acc[h] += v * qtb[((size_t)h << 16) + d];
    }
#pragma unroll
    for (int h = 0; h < HDIM; h++) acc[h] = wred_sum(acc[h]);
    if (lane == 0) {
#pragma unroll
        for (int h = 0; h < HDIM; h++)
            M[((size_t)b * HDIM + h) * NDIM + n] = acc[h] * 0.03125f;
    }
}

// ---------------- qkb + softmax + closest, fused. grid (4, B) ----------------
__global__ __launch_bounds__(256) void k_closest2(const float* __restrict__ gn,
                                                  const float* __restrict__ M,
                                                  const float* __restrict__ Qf,
                                                  const float* __restrict__ abk,
                                                  float* __restrict__ common,
                                                  unsigned short* __restrict__ common_bf) {
    int b = blockIdx.y, t = threadIdx.x;
    int wave = t >> 6, lane = t & 63;
    __shared__ float attn[HDIM][NDIM];
    __shared__ float sqkb[HDIM];
    // qkb[h] = Q[h,b,:]·abk[h,:]
    for (int h = wave; h < HDIM; h += 4) {
        const float* q = Qf + ((size_t)(h * 64 + b)) * DDIM;
        const float* bk = abk + (size_t)h * DDIM;
        float a = 0.f;
        for (int e = lane; e < DDIM; e += 64) a += q[e] * bk[e];
        a = wred_sum(a);
        if (lane == 0) sqkb[h] = a * 0.03125f;
    }
    __syncthreads();
    // softmax per head into LDS
    for (int h = wave; h < HDIM; h += 4) {
        float qa = sqkb[h];
        const float* Mr = M + ((size_t)b * HDIM + h) * NDIM;
        float vals[8];
        float mx = -1e30f;
#pragma unroll
        for (int j = 0; j < 8; j++) {
            vals[j] = Mr[lane + j * 64] + qa;
            mx = fmaxf(mx, vals[j]);
        }
        mx = bfly_max(mx);
        float s = 0.f;
#pragma unroll
        for (int j = 0; j < 8; j++) { vals[j] = __expf(vals[j] - mx); s += vals[j]; }
        s = bfly_sum(s);
        float inv = 1.f / s;
#pragma unroll
        for (int j = 0; j < 8; j++) attn[h][lane + j * 64] = vals[j] * inv;
    }
    __syncthreads();
    // closest[b,h,d] = sum_n attn[h][n] * gn[b,n,d]
    int d = blockIdx.x * 256 + t;
    const float* gb = gn + (size_t)b * NDIM * DDIM + d;
    float acc[HDIM];
#pragma unroll
    for (int h = 0; h < HDIM; h++) acc[h] = 0.f;
#pragma unroll 8
    for (int n = 0; n < NDIM; n++) {
        float v = gb[(size_t)n << 10];
#pragma unroll
        for (int h = 0; h < HDIM; h++) acc[h] += attn[h][n] * v;
    }
#pragma unroll
    for (int h = 0; h < HDIM; h++) {
        size_t o = ((size_t)(b * 9 + 1 + h) << 10) + d;
        common[o] = acc[h];
        common_bf[o] = f2bf(acc[h]);
    }
}

// ---------------- 9x9 attention + diff + dt2 = diff@W2 + ub, fused. grid (B) ----------------
__global__ __launch_bounds__(256) void k_diff2(const float* __restrict__ Qd,
                                               const float* __restrict__ Kd,
                                               const float* __restrict__ common,
                                               const float* __restrict__ g,
                                               const float* __restrict__ W2,
                                               const float* __restrict__ ub,
                                               float* __restrict__ dt2) {
    int b = blockIdx.x, t = threadIdx.x;
    int wave = t >> 6, lane = t & 63;
    __shared__ float smd[81];
    __shared__ float sw[9];
    __shared__ float sdiff[DDIM];
    for (int p = wave; p < 81; p += 4) {
        int i = p / 9, j = p % 9;
        const float* qi = Qd + ((size_t)(b * 9 + i)) * DDIM;
        const float* kj = Kd + ((size_t)(b * 9 + j)) * DDIM;
        float a = 0.f;
        for (int d = lane; d < DDIM; d += 64) a += qi[d] * kj[d];
        a = wred_sum(a);
        if (lane == 0) smd[p] = a * 0.03125f;
    }
    __syncthreads();
    if (t < 9) {
        float mx = -1e30f;
        for (int j = 0; j < 9; j++) mx = fmaxf(mx, smd[t * 9 + j]);
        float e[9], s = 0.f;
        for (int j = 0; j < 9; j++) { e[j] = __expf(smd[t * 9 + j] - mx); s += e[j]; }
        float inv = 1.f / s;
        for (int j = 0; j < 9; j++) smd[t * 9 + j] = e[j] * inv;
    }
    __syncthreads();
    if (t < 9) {
        float a = 0.f;
        for (int i = 0; i < 9; i++) a += smd[i * 9 + t];
        sw[t] = a * (1.f / 9.f);
    }
    __syncthreads();
    for (int d = t; d < DDIM; d += 256) {
        float ci = 0.f;
#pragma unroll
        for (int j = 0; j < 9; j++) ci += sw[j] * common[((size_t)(b * 9 + j) << 10) + d];
        sdiff[d] = g[((size_t)b << 10) + d] - ci;
    }
    __syncthreads();
    // dt2[b,e] = sum_d sdiff[d]*W2[d,e] + ub[e]
    int e = t * 4;
    float4 acc = make_float4(0.f, 0.f, 0.f, 0.f);
#pragma unroll 4
    for (int d = 0; d < DDIM; d++) {
        float s = sdiff[d];
        float4 w = *(const float4*)(W2 + ((size_t)d << 10) + e);
        acc.x += s * w.x; acc.y += s * w.y; acc.z += s * w.z; acc.w += s * w.w;
    }
    float4 bb = *(const float4*)(ub + e);
    acc.x += bb.x; acc.y += bb.y; acc.z += bb.z; acc.w += bb.w;
    *(float4*)(dt2 + ((size_t)b << 10) + e) = acc;
}

// ---------------- main GEMM: relu(Abf@W1t^T + dt2[b]) -> out. 128x128 tile, BK=64,
// global_load_lds width-16 (m97 recipe). grid (8, 98) ----------------
__global__ __launch_bounds__(256) void k_gemm_main(const unsigned short* __restrict__ A,
                                                   const unsigned short* __restrict__ Bw,
                                                   const float* __restrict__ dt2,
                                                   float* __restrict__ out) {
    __shared__ unsigned short As[128 * 64];   // row r: 64 k-elems, 128B/row, unpadded (lds-dma)
    __shared__ unsigned short Bs[128 * 64];
    int t = threadIdx.x;
    int lane = t & 63, wave = t >> 6;
    int quad = lane >> 4, l16 = lane & 15;
    int wr = wave >> 1, wc = wave & 1;
    int m0 = blockIdx.y * 128, n0 = blockIdx.x * 128;
    f32x4 acc[4][4];
#pragma unroll
    for (int i = 0; i < 4; i++)
#pragma unroll
        for (int j = 0; j < 4; j++)
#pragma unroll
            for (int rr = 0; rr < 4; rr++) acc[i][j][rr] = 0.f;

    for (int k0 = 0; k0 < DDIM; k0 += 64) {
#pragma unroll
        for (int cc = 0; cc < 4; cc++) {
            int o = cc * 4096 + t * 16;       // byte offset in 16KB tile
            int r = o >> 7;                    // row (128B per row)
            int ke = (o & 127) >> 1;           // k element within row
            __builtin_amdgcn_global_load_lds(
                (gq_ptr)(const void*)(A + (size_t)(m0 + r) * DDIM + k0 + ke),
                (lds_ptr)(void*)((char*)As + o), 16, 0, 0);
            __builtin_amdgcn_global_load_lds(
                (gq_ptr)(const void*)(Bw + (size_t)(n0 + r) * DDIM + k0 + ke),
                (lds_ptr)(void*)((char*)Bs + o), 16, 0, 0);
        }
        __syncthreads();
#pragma unroll
        for (int ks = 0; ks < 2; ks++) {
            short8 af[4], bf[4];
#pragma unroll
            for (int tm = 0; tm < 4; tm++)
                af[tm] = *(const short8*)(As + (wr * 64 + tm * 16 + l16) * 64 + ks * 32 + quad * 8);
#pragma unroll
            for (int tn = 0; tn < 4; tn++)
                bf[tn] = *(const short8*)(Bs + (wc * 64 + tn * 16 + l16) * 64 + ks * 32 + quad * 8);
#pragma unroll
            for (int tm = 0; tm < 4; tm++)
#pragma unroll
                for (int tn = 0; tn < 4; tn++)
                    acc[tm][tn] = __builtin_amdgcn_mfma_f32_16x16x32_bf16(af[tm], bf[tn], acc[tm][tn], 0, 0, 0);
        }
        __syncthreads();
    }
#pragma unroll
    for (int tm = 0; tm < 4; tm++)
#pragma unroll
        for (int tn = 0; tn < 4; tn++) {
            int col = n0 + wc * 64 + tn * 16 + l16;
#pragma unroll
            for (int rr = 0; rr < 4; rr++) {
                int m = m0 + wr * 64 + tm * 16 + quad * 4 + rr;
                float v = acc[tm][tn][rr] + dt2[((size_t)(m & 63) << 10) + col];
                out[((size_t)m << 10) + col] = fmaxf(v, 0.f);
            }
        }
}

// ---------------- in-place LayerNorm over D ----------------
__global__ __launch_bounds__(256) void k_ln(float* __restrict__ io,
                                            const float* __restrict__ gamma,
                                            const float* __restrict__ beta) {
    size_t row = blockIdx.x;
    float* p = io + row * DDIM;
    int t = threadIdx.x;
    float4 v = *(const float4*)(p + t * 4);
    float s = v.x + v.y + v.z + v.w;
    float s2 = v.x * v.x + v.y * v.y + v.z * v.z + v.w * v.w;
    s = wred_sum(s);
    s2 = wred_sum(s2);
    __shared__ float r1[4], r2[4], mv[2];
    int wave = t >> 6, lane = t & 63;
    if (lane == 0) { r1[wave] = s; r2[wave] = s2; }
    __syncthreads();
    if (t == 0) {
        float S = r1[0] + r1[1] + r1[2] + r1[3];
        float S2 = r2[0] + r2[1] + r2[2] + r2[3];
        float mean = S * (1.f / DDIM);
        float var = S2 * (1.f / DDIM) - mean * mean;
        mv[0] = mean;
        mv[1] = rsqrtf(var + 1e-5f);
    }
    __syncthreads();
    float mean = mv[0], rstd = mv[1];
    float4 gg = *(const float4*)(gamma + t * 4);
    float4 bb = *(const float4*)(beta + t * 4);
    float4 o;
    o.x = (v.x - mean) * rstd * gg.x + bb.x;
    o.y = (v.y - mean) * rstd * gg.y + bb.y;
    o.z = (v.z - mean) * rstd * gg.z + bb.z;
    o.w = (v.w - mean) * rstd * gg.w + bb.w;
    *(float4*)(p + t * 4) = o;
}

extern "C" void kernel_launch(void* const* d_in, const int* in_sizes, int n_in,
                              void* d_out, int out_size, void* d_ws, size_t ws_size,
                              hipStream_t stream) {
    (void)in_sizes; (void)n_in; (void)out_size; (void)ws_size;
    const float* input = (const float*)d_in[0];
    const float* gn    = (const float*)d_in[1];
    const float* aWq   = (const float*)d_in[2];
    const float* abq   = (const float*)d_in[3];
    const float* aWk   = (const float*)d_in[4];
    const float* abk   = (const float*)d_in[5];
    const float* dWq   = (const float*)d_in[6];
    const float* dbq   = (const float*)d_in[7];
    const float* dWk   = (const float*)d_in[8];
    const float* dbk   = (const float*)d_in[9];
    const float* uW    = (const float*)d_in[10];
    const float* ub    = (const float*)d_in[11];
    const float* lng   = (const float*)d_in[12];
    const float* lnb   = (const float*)d_in[13];
    float* out = (float*)d_out;

    float* ws = (float*)d_ws;
    float* g      = ws;                       // 65536
    float* gpart  = g + 65536;                // 458752
    float* Q      = gpart + 458752;           // 524288  [h][b][e] fp32
    float* Qt     = Q + 524288;               // 524288  [h][b][d] fp32
    float* Mbuf   = Qt + 524288;              // 262144  [b][h][n]
    float* common = Mbuf + 262144;            // 589824  [b][9][d]
    float* Qd     = common + 589824;          // 589824
    float* Kd     = Qd + 589824;              // 589824
    float* dt2    = Kd + 589824;              // 65536
    unsigned short* Abf  = (unsigned short*)(dt2 + 65536);  // 12845056
    unsigned short* W1t  = Abf + 12845056;    // 1048576  [e][d]
    unsigned short* aWqT = W1t + 1048576;     // 8388608  [h][e][d]
    unsigned short* aWkb = aWqT + 8388608;    // 8388608  [h][d][e]
    unsigned short* dWqT = aWkb + 8388608;    // 1048576
    unsigned short* dWkT = dWqT + 1048576;    // 1048576
    unsigned short* g_bf = dWkT + 1048576;    // 65536
    unsigned short* Qbf  = g_bf + 65536;      // 524288
    unsigned short* cmbf = Qbf + 524288;      // 589824

    // weight prep (independent)
    k_prep_w<<<dim3(16, 16, 19), 256, 0, stream>>>(aWq, dWq, dWk, uW, aWk,
                                                   aWqT, dWqT, dWkT, W1t, aWkb);
    // input cast + mean
    k_mean_cast<<<dim3(64, 7), 256, 0, stream>>>(input, Abf, gpart);
    k_gfinal<<<64, 256, 0, stream>>>(gpart, g, g_bf, common, cmbf);
    // Q[h,b,:] = g@aWqT[h] + abq[h]   (also bf16 copy)
    k_mfma64<<<dim3(16, 1, 8), 256, 0, stream>>>(g_bf, aWqT, nullptr, abq, nullptr,
        Q, nullptr, Qbf, 0L, 1048576L, 1024L, 65536L, 8);
    // Qt[h,b,:] = Qbf[h]@aWkb[h] (rows d of aWk are k-major over e)
    k_mfma64<<<dim3(16, 1, 8), 256, 0, stream>>>(Qbf, aWkb, nullptr, nullptr, nullptr,
        Qt, nullptr, nullptr, 65536L, 1048576L, 0L, 65536L, 8);
    k_scores<<<dim3(NDIM / 4, BDIM), 256, 0, stream>>>(gn, Qt, Mbuf);
    k_closest2<<<dim3(4, BDIM), 256, 0, stream>>>(gn, Mbuf, Q, abk, common, cmbf);
    // Qd = common@dWqT + dbq ; Kd = common@dWkT + dbk
    k_mfma64<<<dim3(16, 9, 2), 256, 0, stream>>>(cmbf, dWqT, dWkT, dbq, dbk,
        Qd, Kd, nullptr, 0L, 0L, 0L, 0L, 1);
    k_diff2<<<BDIM, 256, 0, stream>>>(Qd, Kd, common, g, uW + (size_t)DDIM * DDIM, ub, dt2);
    k_gemm_main<<<dim3(8, 98), 256, 0, stream>>>(Abf, W1t, dt2, out);
    k_ln<<<SDIM * BDIM, 256, 0, stream>>>(out, lng, lnb);
}

// Round 3
// 520.011 us; speedup vs baseline: 1.6918x; 1.3489x over previous
//
#include <hip/hip_runtime.h>

#define SDIM 196
#define BDIM 64
#define NDIM 512
#define DDIM 1024
#define HDIM 8

typedef __attribute__((ext_vector_type(8))) short short8;
typedef __attribute__((ext_vector_type(8))) unsigned short ushort8;
typedef __attribute__((ext_vector_type(4))) unsigned short ushort4v;
typedef __attribute__((ext_vector_type(4))) float f32x4;

typedef const __attribute__((address_space(1))) unsigned int* gq_ptr;
typedef __attribute__((address_space(3))) unsigned int* lds_ptr;

__device__ __forceinline__ unsigned short f2bf(float f) {
    unsigned int x = __float_as_uint(f);
    x += 0x7fffu + ((x >> 16) & 1u);   // RNE
    return (unsigned short)(x >> 16);
}

__device__ __forceinline__ float wred_sum(float v) {
#pragma unroll
    for (int off = 32; off > 0; off >>= 1) v += __shfl_down(v, off);
    return v;
}

// ---------------- input -> bf16 copy + partial sums over s (7 chunks of 28) ----------------
__global__ __launch_bounds__(256) void k_mean_cast(const float* __restrict__ in,
                                                   unsigned short* __restrict__ Abf,
                                                   float* __restrict__ gpart) {
    int idx4 = blockIdx.x * 256 + threadIdx.x;   // 0..16383 over B*D/4
    int z = blockIdx.y;                           // 0..6
    size_t base = (size_t)idx4 * 4;
    float4 acc = make_float4(0.f, 0.f, 0.f, 0.f);
    int s0 = z * 28;
    for (int s = s0; s < s0 + 28; s++) {
        float4 v = *(const float4*)(in + (size_t)s * 65536 + base);
        acc.x += v.x; acc.y += v.y; acc.z += v.z; acc.w += v.w;
        ushort4v u;
        u[0] = f2bf(v.x); u[1] = f2bf(v.y); u[2] = f2bf(v.z); u[3] = f2bf(v.w);
        *(ushort4v*)(Abf + (size_t)s * 65536 + base) = u;
    }
    *(float4*)(gpart + (size_t)z * 65536 + base) = acc;
}

// ---------------- finalize g (fp32 + bf16), write common row 0 ----------------
__global__ __launch_bounds__(256) void k_gfinal(const float* __restrict__ gpart,
                                                float* __restrict__ g,
                                                unsigned short* __restrict__ g_bf,
                                                float* __restrict__ common,
                                                unsigned short* __restrict__ common_bf) {
    int idx4 = blockIdx.x * 256 + threadIdx.x;
    size_t base = (size_t)idx4 * 4;
    float4 s = make_float4(0.f, 0.f, 0.f, 0.f);
#pragma unroll
    for (int z = 0; z < 7; z++) {
        float4 v = *(const float4*)(gpart + (size_t)z * 65536 + base);
        s.x += v.x; s.y += v.y; s.z += v.z; s.w += v.w;
    }
    const float r = 1.f / (float)SDIM;
    s.x *= r; s.y *= r; s.z *= r; s.w *= r;
    *(float4*)(g + base) = s;
    ushort4v u;
    u[0] = f2bf(s.x); u[1] = f2bf(s.y); u[2] = f2bf(s.z); u[3] = f2bf(s.w);
    *(ushort4v*)(g_bf + base) = u;
    int b = (int)(base >> 10), d = (int)(base & 1023);
    size_t o = ((size_t)b * 9) * DDIM + d;
    *(float4*)(common + o) = s;
    *(ushort4v*)(common_bf + o) = u;
}

// ---------------- all weight casts / transposes in one launch ----------------
// z<8: aWq[h] T ; z=8: dWq T ; z=9: dWk T ; z=10: W1 T ; z=11: W2 T ; z 12..19: aWk[h] copy-cast
__global__ __launch_bounds__(256) void k_prep_w(const float* __restrict__ aWq,
                                                const float* __restrict__ dWq,
                                                const float* __restrict__ dWk,
                                                const float* __restrict__ uW,
                                                const float* __restrict__ aWk,
                                                unsigned short* __restrict__ aWqT,
                                                unsigned short* __restrict__ dWqT,
                                                unsigned short* __restrict__ dWkT,
                                                unsigned short* __restrict__ W1t,
                                                unsigned short* __restrict__ W2T,
                                                unsigned short* __restrict__ aWkb) {
    __shared__ float tile[64][65];
    int z = blockIdx.z;
    const float* src; unsigned short* dst; bool tr = true;
    if (z < 8)       { src = aWq + (size_t)z * 1048576; dst = aWqT + (size_t)z * 1048576; }
    else if (z == 8) { src = dWq; dst = dWqT; }
    else if (z == 9) { src = dWk; dst = dWkT; }
    else if (z == 10){ src = uW;  dst = W1t; }
    else if (z == 11){ src = uW + 1048576; dst = W2T; }
    else             { src = aWk + (size_t)(z - 12) * 1048576; dst = aWkb + (size_t)(z - 12) * 1048576; tr = false; }
    int d0 = blockIdx.y * 64, e0 = blockIdx.x * 64, t = threadIdx.x;
    if (tr) {
        for (int rep = 0; rep < 16; rep++) {
            int idx = rep * 256 + t;
            int dl = idx >> 6, el = idx & 63;
            tile[dl][el] = src[(size_t)(d0 + dl) * DDIM + e0 + el];
        }
        __syncthreads();
        for (int rep = 0; rep < 16; rep++) {
            int idx = rep * 256 + t;
            int el = idx >> 6, dl = idx & 63;
            dst[(size_t)(e0 + el) * DDIM + d0 + dl] = f2bf(tile[dl][el]);
        }
    } else {
        for (int rep = 0; rep < 16; rep++) {
            int idx = rep * 256 + t;
            int dl = idx >> 6, el = idx & 63;
            size_t o = (size_t)(d0 + dl) * DDIM + e0 + el;
            dst[o] = f2bf(src[o]);
        }
    }
}

// ---------------- generic bf16 MFMA GEMM, 64x64 tile, K=1024, ld=1024 ----------------
__global__ __launch_bounds__(256) void k_mfma64(const unsigned short* __restrict__ A,
                                                const unsigned short* __restrict__ B0,
                                                const unsigned short* __restrict__ B1,
                                                const float* __restrict__ bias0,
                                                const float* __restrict__ bias1,
                                                float* __restrict__ C0,
                                                float* __restrict__ C1,
                                                unsigned short* __restrict__ Cbf,
                                                long sA, long sB, long sBias, long sC,
                                                int zsplit) {
    __shared__ unsigned short As[64][40];
    __shared__ unsigned short Bs[64][40];
    int z = blockIdx.z;
    const unsigned short* Bp; const float* bp; float* Cp; int zz;
    if (z < zsplit) { Bp = B0; bp = bias0; Cp = C0; zz = z; }
    else            { Bp = B1; bp = bias1; Cp = C1; zz = z - zsplit; }
    A  += (size_t)zz * sA;
    Bp += (size_t)zz * sB;
    if (bp) bp += (size_t)zz * sBias;
    Cp += (size_t)zz * sC;
    unsigned short* Cb = Cbf ? Cbf + (size_t)zz * sC : nullptr;

    int t = threadIdx.x;
    int lane = t & 63, wave = t >> 6;
    int quad = lane >> 4, l16 = lane & 15;
    int wr = wave >> 1, wc = wave & 1;
    int m0 = blockIdx.y * 64, n0 = blockIdx.x * 64;
    f32x4 acc[2][2];
#pragma unroll
    for (int i = 0; i < 2; i++)
#pragma unroll
        for (int j = 0; j < 2; j++)
#pragma unroll
            for (int rr = 0; rr < 4; rr++) acc[i][j][rr] = 0.f;
    int r = t >> 2, c = (t & 3) * 8;
    for (int k0 = 0; k0 < DDIM; k0 += 32) {
        *(ushort8*)&As[r][c] = *(const ushort8*)(A  + (size_t)(m0 + r) * DDIM + k0 + c);
        *(ushort8*)&Bs[r][c] = *(const ushort8*)(Bp + (size_t)(n0 + r) * DDIM + k0 + c);
        __syncthreads();
        short8 a0 = *(const short8*)&As[wr * 32 + l16][quad * 8];
        short8 a1 = *(const short8*)&As[wr * 32 + 16 + l16][quad * 8];
        short8 b0 = *(const short8*)&Bs[wc * 32 + l16][quad * 8];
        short8 b1 = *(const short8*)&Bs[wc * 32 + 16 + l16][quad * 8];
        acc[0][0] = __builtin_amdgcn_mfma_f32_16x16x32_bf16(a0, b0, acc[0][0], 0, 0, 0);
        acc[0][1] = __builtin_amdgcn_mfma_f32_16x16x32_bf16(a0, b1, acc[0][1], 0, 0, 0);
        acc[1][0] = __builtin_amdgcn_mfma_f32_16x16x32_bf16(a1, b0, acc[1][0], 0, 0, 0);
        acc[1][1] = __builtin_amdgcn_mfma_f32_16x16x32_bf16(a1, b1, acc[1][1], 0, 0, 0);
        __syncthreads();
    }
#pragma unroll
    for (int tm = 0; tm < 2; tm++)
#pragma unroll
        for (int tn = 0; tn < 2; tn++) {
            int col = n0 + wc * 32 + tn * 16 + l16;
            float bb = bp ? bp[col] : 0.f;
#pragma unroll
            for (int rr = 0; rr < 4; rr++) {
                int m = m0 + wr * 32 + tm * 16 + quad * 4 + rr;
                float v = acc[tm][tn][rr] + bb;
                Cp[(size_t)m * DDIM + col] = v;
                if (Cb) Cb[(size_t)m * DDIM + col] = f2bf(v);
            }
        }
}

// ---------------- fused aggregated attention (flash-style over n), grid (8, B) ----------------
// chunk = 64 n rows; partial (m, l, O) per (chunk, b, h) written to ws.
__global__ __launch_bounds__(256) void k_agg(const float* __restrict__ gn,
                                             const float* __restrict__ Qt,
                                             const float* __restrict__ Qf,
                                             const float* __restrict__ abk,
                                             float* __restrict__ Opart,
                                             float* __restrict__ ml) {
    int b = blockIdx.y, chunk = blockIdx.x, t = threadIdx.x;
    int wave = t >> 6, lane = t & 63;
    __shared__ float sQt[8][1024];    // 32KB
    __shared__ float srow[8][1024];   // 32KB
    __shared__ float sS[8][8];        // [h][row]
    __shared__ float sEt[8][8];       // [row][h]
    __shared__ float sqkb[8];
    // load Qt[b] rows (layout [h][b][d])
#pragma unroll
    for (int h = 0; h < 8; h++)
        *(float4*)&sQt[h][t * 4] = *(const float4*)(Qt + ((size_t)(h * 64 + b) << 10) + t * 4);
    // qkb[h] = Q[h,b,:]·abk[h,:]  (raw)
    for (int h = wave; h < 8; h += 4) {
        const float* q = Qf + ((size_t)(h * 64 + b) << 10);
        const float* bk = abk + ((size_t)h << 10);
        float a = 0.f;
        for (int e = lane; e < 1024; e += 64) a += q[e] * bk[e];
        a = wred_sum(a);
        if (lane == 0) sqkb[h] = a;
    }
    float O[8][4];
    float m[8], l[8];
#pragma unroll
    for (int h = 0; h < 8; h++) {
        m[h] = -1e30f; l[h] = 0.f;
#pragma unroll
        for (int j = 0; j < 4; j++) O[h][j] = 0.f;
    }
    const float* gnb = gn + (((size_t)b * NDIM + chunk * 64) << 10);
    int r0 = wave * 2, r1 = r0 + 1;

    for (int tile = 0; tile < 8; tile++) {
        __syncthreads();   // prev-tile consumers done (also covers sQt/sqkb on tile 0)
        // stage 8 rows; wave stages its 2 rows via registers (kept for the dots)
        float4 rv[2][4];
#pragma unroll
        for (int rr = 0; rr < 2; rr++) {
            const float* src = gnb + ((size_t)(tile * 8 + wave * 2 + rr) << 10);
#pragma unroll
            for (int j = 0; j < 4; j++) {
                float4 v = *(const float4*)(src + j * 256 + lane * 4);
                rv[rr][j] = v;
                *(float4*)&srow[wave * 2 + rr][j * 256 + lane * 4] = v;
            }
        }
        // scores for this wave's 2 rows, all 8 heads (fp32, exact)
#pragma unroll
        for (int h = 0; h < 8; h++) {
            float a0 = 0.f, a1 = 0.f;
#pragma unroll
            for (int j = 0; j < 4; j++) {
                float4 q = *(const float4*)&sQt[h][j * 256 + lane * 4];
                a0 += q.x * rv[0][j].x + q.y * rv[0][j].y + q.z * rv[0][j].z + q.w * rv[0][j].w;
                a1 += q.x * rv[1][j].x + q.y * rv[1][j].y + q.z * rv[1][j].z + q.w * rv[1][j].w;
            }
            a0 = wred_sum(a0); a1 = wred_sum(a1);
            if (lane == 0) {
                sS[h][r0] = (a0 + sqkb[h]) * 0.03125f;
                sS[h][r1] = (a1 + sqkb[h]) * 0.03125f;
            }
        }
        __syncthreads();
        // online-softmax bookkeeping (redundant per thread; identical values)
        float alpha[8];
#pragma unroll
        for (int h = 0; h < 8; h++) {
            float tm = sS[h][0];
#pragma unroll
            for (int r = 1; r < 8; r++) tm = fmaxf(tm, sS[h][r]);
            float mn = fmaxf(m[h], tm);
            alpha[h] = __expf(m[h] - mn);
            m[h] = mn;
        }
        if (t < 64) {
            int r = t >> 3, h = t & 7;
            sEt[r][h] = __expf(sS[h][r] - m[h]);
        }
        __syncthreads();
#pragma unroll
        for (int h = 0; h < 8; h++) {
            l[h] *= alpha[h];
#pragma unroll
            for (int j = 0; j < 4; j++) O[h][j] *= alpha[h];
        }
#pragma unroll
        for (int r = 0; r < 8; r++) {
            float4 e0 = *(const float4*)&sEt[r][0];
            float4 e1 = *(const float4*)&sEt[r][4];
            float4 v = *(const float4*)&srow[r][t * 4];
            float ee[8] = {e0.x, e0.y, e0.z, e0.w, e1.x, e1.y, e1.z, e1.w};
#pragma unroll
            for (int h = 0; h < 8; h++) {
                O[h][0] += ee[h] * v.x; O[h][1] += ee[h] * v.y;
                O[h][2] += ee[h] * v.z; O[h][3] += ee[h] * v.w;
                l[h] += ee[h];
            }
        }
    }
    // write partials
    size_t pb = ((size_t)chunk * 64 + b) * 8;
#pragma unroll
    for (int h = 0; h < 8; h++)
        *(float4*)(Opart + (pb + h) * 1024 + t * 4) = make_float4(O[h][0], O[h][1], O[h][2], O[h][3]);
    if (t == 0) {
#pragma unroll
        for (int h = 0; h < 8; h++) {
            ml[(pb + h) * 2 + 0] = m[h];
            ml[(pb + h) * 2 + 1] = l[h];
        }
    }
}

// ---------------- combine 8 chunk-partials -> common rows 1..8 (+bf16) ----------------
__global__ __launch_bounds__(256) void k_agg_reduce(const float* __restrict__ Opart,
                                                    const float* __restrict__ ml,
                                                    float* __restrict__ common,
                                                    unsigned short* __restrict__ common_bf) {
    int b = blockIdx.y, t = threadIdx.x;
    int d = blockIdx.x * 256 + t;
#pragma unroll
    for (int h = 0; h < 8; h++) {
        float mc[8], lc[8];
        float M = -1e30f;
#pragma unroll
        for (int c = 0; c < 8; c++) {
            size_t p = (((size_t)c * 64 + b) * 8 + h) * 2;
            mc[c] = ml[p]; lc[c] = ml[p + 1];
            M = fmaxf(M, mc[c]);
        }
        float den = 0.f, num = 0.f;
#pragma unroll
        for (int c = 0; c < 8; c++) {
            float sc = __expf(mc[c] - M);
            den += sc * lc[c];
            num += sc * Opart[(((size_t)c * 64 + b) * 8 + h) * 1024 + d];
        }
        float o = num / den;
        size_t off = ((size_t)(b * 9 + 1 + h) << 10) + d;
        common[off] = o;
        common_bf[off] = f2bf(o);
    }
}

// ---------------- 9x9 attention + diff -> bf16, grid (B) ----------------
__global__ __launch_bounds__(256) void k_diff(const float* __restrict__ Qd,
                                              const float* __restrict__ Kd,
                                              const float* __restrict__ common,
                                              const float* __restrict__ g,
                                              unsigned short* __restrict__ diffb_bf) {
    int b = blockIdx.x, t = threadIdx.x;
    int wave = t >> 6, lane = t & 63;
    __shared__ float sQ[9 * 1024];
    __shared__ float sK[9 * 1024];
    __shared__ float smd[81];
    __shared__ float sw[9];
    const float* Qb = Qd + (size_t)b * 9216;
    const float* Kb = Kd + (size_t)b * 9216;
    for (int i = t; i < 2304; i += 256) {
        *(float4*)&sQ[i * 4] = *(const float4*)(Qb + (size_t)i * 4);
        *(float4*)&sK[i * 4] = *(const float4*)(Kb + (size_t)i * 4);
    }
    __syncthreads();
    for (int p = wave; p < 81; p += 4) {
        int i = p / 9, j = p % 9;
        const float* qi = sQ + i * 1024;
        const float* kj = sK + j * 1024;
        float a = 0.f;
#pragma unroll
        for (int jj = 0; jj < 4; jj++) {
            float4 q = *(const float4*)(qi + jj * 256 + lane * 4);
            float4 k = *(const float4*)(kj + jj * 256 + lane * 4);
            a += q.x * k.x + q.y * k.y + q.z * k.z + q.w * k.w;
        }
        a = wred_sum(a);
        if (lane == 0) smd[p] = a * 0.03125f;
    }
    __syncthreads();
    if (t < 9) {
        float mx = -1e30f;
        for (int j = 0; j < 9; j++) mx = fmaxf(mx, smd[t * 9 + j]);
        float e[9], s = 0.f;
        for (int j = 0; j < 9; j++) { e[j] = __expf(smd[t * 9 + j] - mx); s += e[j]; }
        float inv = 1.f / s;
        for (int j = 0; j < 9; j++) smd[t * 9 + j] = e[j] * inv;
    }
    __syncthreads();
    if (t < 9) {
        float a = 0.f;
        for (int i = 0; i < 9; i++) a += smd[i * 9 + t];
        sw[t] = a * (1.f / 9.f);
    }
    __syncthreads();
    int d = t * 4;
    float4 ci = make_float4(0.f, 0.f, 0.f, 0.f);
#pragma unroll
    for (int j = 0; j < 9; j++) {
        float w = sw[j];
        float4 cv = *(const float4*)(common + ((size_t)(b * 9 + j) << 10) + d);
        ci.x += w * cv.x; ci.y += w * cv.y; ci.z += w * cv.z; ci.w += w * cv.w;
    }
    float4 gv = *(const float4*)(g + ((size_t)b << 10) + d);
    ushort4v u;
    u[0] = f2bf(gv.x - ci.x); u[1] = f2bf(gv.y - ci.y);
    u[2] = f2bf(gv.z - ci.z); u[3] = f2bf(gv.w - ci.w);
    *(ushort4v*)(diffb_bf + ((size_t)b << 10) + d) = u;
}

// ---------------- main GEMM: relu(Abf@W1t^T + dt2[b]) -> out. 128x128, BK=64, lds-dma ----------------
__global__ __launch_bounds__(256) void k_gemm_main(const unsigned short* __restrict__ A,
                                                   const unsigned short* __restrict__ Bw,
                                                   const float* __restrict__ dt2,
                                                   float* __restrict__ out) {
    __shared__ unsigned short As[128 * 64];
    __shared__ unsigned short Bs[128 * 64];
    int t = threadIdx.x;
    int lane = t & 63, wave = t >> 6;
    int quad = lane >> 4, l16 = lane & 15;
    int wr = wave >> 1, wc = wave & 1;
    int m0 = blockIdx.y * 128, n0 = blockIdx.x * 128;
    f32x4 acc[4][4];
#pragma unroll
    for (int i = 0; i < 4; i++)
#pragma unroll
        for (int j = 0; j < 4; j++)
#pragma unroll
            for (int rr = 0; rr < 4; rr++) acc[i][j][rr] = 0.f;

    for (int k0 = 0; k0 < DDIM; k0 += 64) {
#pragma unroll
        for (int cc = 0; cc < 4; cc++) {
            int o = cc * 4096 + t * 16;
            int r = o >> 7;
            int ke = (o & 127) >> 1;
            __builtin_amdgcn_global_load_lds(
                (gq_ptr)(const void*)(A + (size_t)(m0 + r) * DDIM + k0 + ke),
                (lds_ptr)(void*)((char*)As + o), 16, 0, 0);
            __builtin_amdgcn_global_load_lds(
                (gq_ptr)(const void*)(Bw + (size_t)(n0 + r) * DDIM + k0 + ke),
                (lds_ptr)(void*)((char*)Bs + o), 16, 0, 0);
        }
        __syncthreads();
#pragma unroll
        for (int ks = 0; ks < 2; ks++) {
            short8 af[4], bf[4];
#pragma unroll
            for (int tm = 0; tm < 4; tm++)
                af[tm] = *(const short8*)(As + (wr * 64 + tm * 16 + l16) * 64 + ks * 32 + quad * 8);
#pragma unroll
            for (int tn = 0; tn < 4; tn++)
                bf[tn] = *(const short8*)(Bs + (wc * 64 + tn * 16 + l16) * 64 + ks * 32 + quad * 8);
#pragma unroll
            for (int tm = 0; tm < 4; tm++)
#pragma unroll
                for (int tn = 0; tn < 4; tn++)
                    acc[tm][tn] = __builtin_amdgcn_mfma_f32_16x16x32_bf16(af[tm], bf[tn], acc[tm][tn], 0, 0, 0);
        }
        __syncthreads();
    }
#pragma unroll
    for (int tm = 0; tm < 4; tm++)
#pragma unroll
        for (int tn = 0; tn < 4; tn++) {
            int col = n0 + wc * 64 + tn * 16 + l16;
#pragma unroll
            for (int rr = 0; rr < 4; rr++) {
                int m = m0 + wr * 64 + tm * 16 + quad * 4 + rr;
                float v = acc[tm][tn][rr] + dt2[((size_t)(m & 63) << 10) + col];
                out[((size_t)m << 10) + col] = fmaxf(v, 0.f);
            }
        }
}

// ---------------- in-place LayerNorm over D ----------------
__global__ __launch_bounds__(256) void k_ln(float* __restrict__ io,
                                            const float* __restrict__ gamma,
                                            const float* __restrict__ beta) {
    size_t row = blockIdx.x;
    float* p = io + row * DDIM;
    int t = threadIdx.x;
    float4 v = *(const float4*)(p + t * 4);
    float s = v.x + v.y + v.z + v.w;
    float s2 = v.x * v.x + v.y * v.y + v.z * v.z + v.w * v.w;
    s = wred_sum(s);
    s2 = wred_sum(s2);
    __shared__ float r1[4], r2[4], mv[2];
    int wave = t >> 6, lane = t & 63;
    if (lane == 0) { r1[wave] = s; r2[wave] = s2; }
    __syncthreads();
    if (t == 0) {
        float S = r1[0] + r1[1] + r1[2] + r1[3];
        float S2 = r2[0] + r2[1] + r2[2] + r2[3];
        float mean = S * (1.f / DDIM);
        float var = S2 * (1.f / DDIM) - mean * mean;
        mv[0] = mean;
        mv[1] = rsqrtf(var + 1e-5f);
    }
    __syncthreads();
    float mean = mv[0], rstd = mv[1];
    float4 gg = *(const float4*)(gamma + t * 4);
    float4 bb = *(const float4*)(beta + t * 4);
    float4 o;
    o.x = (v.x - mean) * rstd * gg.x + bb.x;
    o.y = (v.y - mean) * rstd * gg.y + bb.y;
    o.z = (v.z - mean) * rstd * gg.z + bb.z;
    o.w = (v.w - mean) * rstd * gg.w + bb.w;
    *(float4*)(p + t * 4) = o;
}

extern "C" void kernel_launch(void* const* d_in, const int* in_sizes, int n_in,
                              void* d_out, int out_size, void* d_ws, size_t ws_size,
                              hipStream_t stream) {
    (void)in_sizes; (void)n_in; (void)out_size; (void)ws_size;
    const float* input = (const float*)d_in[0];
    const float* gn    = (const float*)d_in[1];
    const float* aWq   = (const float*)d_in[2];
    const float* abq   = (const float*)d_in[3];
    const float* aWk   = (const float*)d_in[4];
    const float* abk   = (const float*)d_in[5];
    const float* dWq   = (const float*)d_in[6];
    const float* dbq   = (const float*)d_in[7];
    const float* dWk   = (const float*)d_in[8];
    const float* dbk   = (const float*)d_in[9];
    const float* uW    = (const float*)d_in[10];
    const float* ub    = (const float*)d_in[11];
    const float* lng   = (const float*)d_in[12];
    const float* lnb   = (const float*)d_in[13];
    float* out = (float*)d_out;

    float* ws = (float*)d_ws;
    float* g      = ws;                       // 65536
    float* gpart  = g + 65536;                // 458752
    float* Q      = gpart + 458752;           // 524288  [h][b][d]
    float* Qt     = Q + 524288;               // 524288  [h][b][d]
    float* common = Qt + 524288;              // 589824  [b][9][d]
    float* dt2    = common + 589824;          // 65536
    float* Opart  = dt2 + 65536;              // 4194304 [c][b][h][d]
    float* ml     = Opart + 4194304;          // 8192
    float* Qd     = Opart;                    // alias: Opart dead after k_agg_reduce
    float* Kd     = Opart + 589824;
    unsigned short* Abf  = (unsigned short*)(ml + 8192);   // 12845056
    unsigned short* W1t  = Abf + 12845056;    // 1048576
    unsigned short* W2T  = W1t + 1048576;     // 1048576
    unsigned short* aWqT = W2T + 1048576;     // 8388608
    unsigned short* aWkb = aWqT + 8388608;    // 8388608
    unsigned short* dWqT = aWkb + 8388608;    // 1048576
    unsigned short* dWkT = dWqT + 1048576;    // 1048576
    unsigned short* g_bf = dWkT + 1048576;    // 65536
    unsigned short* Qbf  = g_bf + 65536;      // 524288
    unsigned short* cmbf = Qbf + 524288;      // 589824
    unsigned short* dfbf = cmbf + 589824;     // 65536

    k_prep_w<<<dim3(16, 16, 20), 256, 0, stream>>>(aWq, dWq, dWk, uW, aWk,
                                                   aWqT, dWqT, dWkT, W1t, W2T, aWkb);
    k_mean_cast<<<dim3(64, 7), 256, 0, stream>>>(input, Abf, gpart);
    k_gfinal<<<64, 256, 0, stream>>>(gpart, g, g_bf, common, cmbf);
    // Q[h,b,:] = g@aWqT[h] + abq[h]  (fp32 + bf16)
    k_mfma64<<<dim3(16, 1, 8), 256, 0, stream>>>(g_bf, aWqT, nullptr, abq, nullptr,
        Q, nullptr, Qbf, 0L, 1048576L, 1024L, 65536L, 8);
    // Qt[h,b,:] = Qbf[h]@aWkb[h]
    k_mfma64<<<dim3(16, 1, 8), 256, 0, stream>>>(Qbf, aWkb, nullptr, nullptr, nullptr,
        Qt, nullptr, nullptr, 65536L, 1048576L, 0L, 65536L, 8);
    k_agg<<<dim3(8, BDIM), 256, 0, stream>>>(gn, Qt, Q, abk, Opart, ml);
    k_agg_reduce<<<dim3(4, BDIM), 256, 0, stream>>>(Opart, ml, common, cmbf);
    // Qd = common@dWqT + dbq ; Kd = common@dWkT + dbk
    k_mfma64<<<dim3(16, 9, 2), 256, 0, stream>>>(cmbf, dWqT, dWkT, dbq, dbk,
        Qd, Kd, nullptr, 0L, 0L, 0L, 0L, 1);
    k_diff<<<BDIM, 256, 0, stream>>>(Qd, Kd, common, g, dfbf);
    // dt2 = diffb@W2 + ub
    k_mfma64<<<dim3(16, 1, 1), 256, 0, stream>>>(dfbf, W2T, nullptr, ub, nullptr,
        dt2, nullptr, nullptr, 0L, 0L, 0L, 0L, 1);
    k_gemm_main<<<dim3(8, 98), 256, 0, stream>>>(Abf, W1t, dt2, out);
    k_ln<<<SDIM * BDIM, 256, 0, stream>>>(out, lng, lnb);
}